// Round 6
// baseline (210.503 us; speedup 1.0000x reference)
//
#include <hip/hip_runtime.h>
#include <hip/hip_cooperative_groups.h>

namespace cg = cooperative_groups;

// Flash attention fwd, B=2 S=8192 D=64.
// Round 5: single cooperative kernel, 3 phases:
//   1) K,V f32->bf16 (ws)   2) flash attn, 256 blocks x 8 waves, BQ=256,
//      split-K=4, K/V tiles LDS-staged (XOR-swizzled, shared by all 8 waves)
//   3) split-K merge.
// Fragment/softmax/exchange math identical to round-4 (verified, absmax 7.3e-4).

#define SEQ 8192
#define DH  64

typedef __attribute__((ext_vector_type(8)))  short short8v;
typedef __attribute__((ext_vector_type(4)))  float f32x4;
typedef __attribute__((ext_vector_type(16))) float f32x16;

__device__ __forceinline__ uint f2bf(float f) {
    uint u = __float_as_uint(f);
    return (u + 0x7FFFu + ((u >> 16) & 1u)) >> 16;  // RNE
}

// ws layout (needs 21,495,808 B)
#define WS_VB 2097152
#define WS_OP 4194304
#define WS_ML 20971520
#define WS_NEED 21495808ULL

// ============ phase 1: K,V -> bf16 ============
__device__ __forceinline__ void phase_prep(const float* __restrict__ K, const float* __restrict__ V,
                                           ushort* __restrict__ Kb, ushort* __restrict__ Vb,
                                           int bid, int tid) {
    size_t base = ((size_t)bid * 512 + tid) * 8;   // 131072 threads x 8 elts = 2*8192*64
    float4 a = *(const float4*)(K + base);
    float4 c = *(const float4*)(K + base + 4);
    uint4 ko;
    ko.x = f2bf(a.x) | (f2bf(a.y) << 16);
    ko.y = f2bf(a.z) | (f2bf(a.w) << 16);
    ko.z = f2bf(c.x) | (f2bf(c.y) << 16);
    ko.w = f2bf(c.z) | (f2bf(c.w) << 16);
    *(uint4*)(Kb + base) = ko;
    float4 d = *(const float4*)(V + base);
    float4 e = *(const float4*)(V + base + 4);
    uint4 vo;
    vo.x = f2bf(d.x) | (f2bf(d.y) << 16);
    vo.y = f2bf(d.z) | (f2bf(d.w) << 16);
    vo.z = f2bf(e.x) | (f2bf(e.y) << 16);
    vo.w = f2bf(e.z) | (f2bf(e.w) << 16);
    *(uint4*)(Vb + base) = vo;
}

// ============ phase 2: flash attention, split-K=4 ============
__device__ __forceinline__ void phase_attn(const float* __restrict__ Q,
                                           const ushort* __restrict__ Kb, const ushort* __restrict__ Vb,
                                           float* __restrict__ Opart, float* __restrict__ Ml,
                                           int bid, int tid) {
    __shared__ __align__(16) char smem[32768];  // 2 x (K 8KB + V 8KB)

    const int wk = (bid & 7) * 32 + (bid >> 3);  // XCD swizzle: 32 consecutive wk per XCD
    const int qt = wk & 31, quarter = (wk >> 5) & 3, b = wk >> 7;
    const int q0 = qt * 256, kq0 = quarter * 2048;
    const int lane = tid & 63, w = tid >> 6;
    const int q = lane & 31, hi = lane >> 5;

    // ---- Q fragments (x0.125 folded) ----
    short8v qf[4];
    {
        const float* qr = Q + ((size_t)b * SEQ + q0 + 32 * w + q) * DH + 8 * hi;
#pragma unroll
        for (int t = 0; t < 4; ++t) {
            float4 a = *(const float4*)(qr + 16 * t);
            float4 c = *(const float4*)(qr + 16 * t + 4);
            union { uint u[4]; short8v v; } cv;
            cv.u[0] = f2bf(a.x * 0.125f) | (f2bf(a.y * 0.125f) << 16);
            cv.u[1] = f2bf(a.z * 0.125f) | (f2bf(a.w * 0.125f) << 16);
            cv.u[2] = f2bf(c.x * 0.125f) | (f2bf(c.y * 0.125f) << 16);
            cv.u[3] = f2bf(c.z * 0.125f) | (f2bf(c.w * 0.125f) << 16);
            qf[t] = cv.v;
        }
    }

    // ---- staging assignment: thread = (key, ocho) ----
    const int skey = tid >> 3, ocho = tid & 7;
    const ushort* Ksrc = Kb + ((size_t)b * SEQ + kq0 + skey) * DH + 8 * ocho;
    const ushort* Vsrc = Vb + ((size_t)b * SEQ + kq0 + skey) * DH + 8 * ocho;

    short8v kreg, vreg;
    auto stage_load = [&](int kt) {
        kreg = *(const short8v*)(Ksrc + (size_t)kt * 64 * DH);
        vreg = *(const short8v*)(Vsrc + (size_t)kt * 64 * DH);
    };
    auto stage_write = [&](int p) {
        char* kbp = smem + p * 16384;
        char* vbp = kbp + 8192;
        // K: row=key, slot=ocho^(key&7)  (swizzled b128 write)
        *(short8v*)(kbp + skey * 128 + ((ocho ^ (skey & 7)) << 4)) = kreg;
        // V transposed: Vt[d][key], u16 writes, slot=(key>>3)^(d&7)
#pragma unroll
        for (int i = 0; i < 8; ++i) {
            int d = 8 * ocho + i;
            *(ushort*)(vbp + d * 128 + (((skey >> 3) ^ i) << 4) + (skey & 7) * 2) = (ushort)vreg[i];
        }
    };

    f32x16 o0, o1;
#pragma unroll
    for (int j = 0; j < 16; ++j) { o0[j] = 0.f; o1[j] = 0.f; }
    float m = -1e30f, l = 0.f;

    stage_load(0); stage_write(0); __syncthreads();

    for (int kt = 0; kt < 32; ++kt) {
        const int p = kt & 1;
        if (kt + 1 < 32) stage_load(kt + 1);
        char* kbp = smem + p * 16384;
        char* vbp = kbp + 8192;

        // ---- K fragments + S^T = K Q^T ----
        short8v ka[8];
#pragma unroll
        for (int kb2 = 0; kb2 < 2; ++kb2)
#pragma unroll
            for (int t = 0; t < 4; ++t) {
                int row = kb2 * 32 + q;
                ka[kb2 * 4 + t] = *(const short8v*)(kbp + row * 128 + (((2 * t + hi) ^ (row & 7)) << 4));
            }
        f32x16 s0, s1;
#pragma unroll
        for (int j = 0; j < 16; ++j) { s0[j] = 0.f; s1[j] = 0.f; }
#pragma unroll
        for (int t = 0; t < 4; ++t) {
            s0 = __builtin_amdgcn_mfma_f32_32x32x16_bf16(ka[t],     qf[t], s0, 0, 0, 0);
            s1 = __builtin_amdgcn_mfma_f32_32x32x16_bf16(ka[4 + t], qf[t], s1, 0, 0, 0);
        }

        // ---- online softmax (lane owns q-row; round-4 verified) ----
        float tm;
        {
            f32x16 tv;
#pragma unroll
            for (int j = 0; j < 16; ++j) tv[j] = fmaxf(s0[j], s1[j]);
#pragma unroll
            for (int j = 0; j < 8; ++j) tv[j] = fmaxf(tv[j], tv[j + 8]);
#pragma unroll
            for (int j = 0; j < 4; ++j) tv[j] = fmaxf(tv[j], tv[j + 4]);
            tm = fmaxf(fmaxf(tv[0], tv[1]), fmaxf(tv[2], tv[3]));
        }
        tm = fmaxf(tm, __shfl_xor(tm, 32));
        float mnew = fmaxf(m, tm);
        if (__any(mnew > m)) {
            float sc = __expf(m - mnew);
            l *= sc;
#pragma unroll
            for (int j = 0; j < 16; ++j) { o0[j] *= sc; o1[j] *= sc; }
            m = mnew;
        }
#pragma unroll
        for (int j = 0; j < 16; ++j) {
            s0[j] = __expf(s0[j] - m);
            s1[j] = __expf(s1[j] - m);
        }
        {
            f32x16 pa;
#pragma unroll
            for (int j = 0; j < 16; ++j) pa[j] = s0[j] + s1[j];
#pragma unroll
            for (int j = 0; j < 8; ++j) pa[j] += pa[j + 8];
#pragma unroll
            for (int j = 0; j < 4; ++j) pa[j] += pa[j + 4];
            float ls = (pa[0] + pa[1]) + (pa[2] + pa[3]);
            ls += __shfl_xor(ls, 32);
            l += ls;
        }

        // ---- pack P -> bf16 words + cross-half exchange -> B-frags ----
        uint W[16];
#pragma unroll
        for (int i = 0; i < 8; ++i) {
#pragma unroll
            for (int c = 0; c < 2; ++c) {
                int kb3 = i >> 2, rg = ((i & 3) << 2) | (c << 1);
                float lo = kb3 ? s1[rg] : s0[rg];
                float hh = kb3 ? s1[rg + 1] : s0[rg + 1];
                uint ww;
                asm("v_cvt_pk_bf16_f32 %0, %1, %2" : "=v"(ww) : "v"(lo), "v"(hh));
                W[2 * i + c] = ww;
            }
        }
        short8v bfrag[4];
#pragma unroll
        for (int kc = 0; kc < 4; ++kc) {
            uint w0 = W[4 * kc], w1 = W[4 * kc + 1], w2 = W[4 * kc + 2], w3 = W[4 * kc + 3];
            uint y02 = hi ? w0 : w2;
            uint z02 = __shfl_xor(y02, 32);
            uint y13 = hi ? w1 : w3;
            uint z13 = __shfl_xor(y13, 32);
            union { uint u[4]; short8v v; } cv;
            cv.u[0] = hi ? z02 : w0;
            cv.u[1] = hi ? z13 : w1;
            cv.u[2] = hi ? w2 : z02;
            cv.u[3] = hi ? w3 : z13;
            bfrag[kc] = cv.v;
        }

        // ---- V fragments + O^T += V^T P^T ----
        short8v va[8];
#pragma unroll
        for (int db = 0; db < 2; ++db)
#pragma unroll
            for (int kc = 0; kc < 4; ++kc) {
                int row = db * 32 + q;
                va[db * 4 + kc] = *(const short8v*)(vbp + row * 128 + (((2 * kc + hi) ^ (row & 7)) << 4));
            }
#pragma unroll
        for (int kc = 0; kc < 4; ++kc) {
            o0 = __builtin_amdgcn_mfma_f32_32x32x16_bf16(va[kc],     bfrag[kc], o0, 0, 0, 0);
            o1 = __builtin_amdgcn_mfma_f32_32x32x16_bf16(va[4 + kc], bfrag[kc], o1, 0, 0, 0);
        }

        if (kt + 1 < 32) stage_write((kt + 1) & 1);
        __syncthreads();
    }

    // ---- epilogue: coalesced partial stores in C-fragment layout ----
    float* Op = Opart + ((((size_t)quarter * 2 + b) * 32 + qt) * 8 + w) * 2048;
#pragma unroll
    for (int j = 0; j < 4; ++j) {
        f32x4 t0 = { o0[4 * j], o0[4 * j + 1], o0[4 * j + 2], o0[4 * j + 3] };
        *(f32x4*)(Op + j * 256 + lane * 4) = t0;
        f32x4 t1 = { o1[4 * j], o1[4 * j + 1], o1[4 * j + 2], o1[4 * j + 3] };
        *(f32x4*)(Op + (4 + j) * 256 + lane * 4) = t1;
    }
    if (hi == 0) {
        float2 v2 = make_float2(m, l);
        *(float2*)(Ml + ((size_t)quarter * 16384 + (size_t)b * 8192 + q0 + 32 * w + q) * 2) = v2;
    }
}

// ============ phase 3: merge 4 partials ============
__device__ __forceinline__ void phase_merge(const float* __restrict__ Opart, const float* __restrict__ Ml,
                                            float* __restrict__ O, int bid, int tid) {
    int g = bid * 512 + tid;           // 131072 = 16384 rows x 8 d-chunks
    int r = g >> 3, d0 = (g & 7) * 8;
    int bb = r >> 13, row = r & 8191;
    int qt = row >> 8, w = (row >> 5) & 7, q = row & 31;
    float mi[4], li[4];
#pragma unroll
    for (int i = 0; i < 4; ++i) {
        float2 v2 = *(const float2*)(Ml + ((size_t)i * 16384 + r) * 2);
        mi[i] = v2.x; li[i] = v2.y;
    }
    float M = fmaxf(fmaxf(mi[0], mi[1]), fmaxf(mi[2], mi[3]));
    float e4[4]; float lsum = 0.f;
#pragma unroll
    for (int i = 0; i < 4; ++i) { e4[i] = __expf(mi[i] - M); lsum += e4[i] * li[i]; }
    float inv = 1.0f / lsum;
    float aAx = 0, aAy = 0, aAz = 0, aAw = 0, aBx = 0, aBy = 0, aBz = 0, aBw = 0;
    const int oh = (d0 >= 32) ? 4 : 0;
    const int s8 = (d0 & 31) >> 3;
#pragma unroll
    for (int i = 0; i < 4; ++i) {
        size_t wb = ((((size_t)i * 2 + bb) * 32 + qt) * 8 + w) * 2048;
        const float* pa = Opart + wb + (size_t)(oh + s8) * 256 + q * 4;          // d0..d0+3 (hi=0)
        const float* pb = Opart + wb + (size_t)(oh + s8) * 256 + (q + 32) * 4;   // d0+4..d0+7 (hi=1)
        float4 va4 = *(const float4*)pa;
        float4 vb4 = *(const float4*)pb;
        aAx += e4[i] * va4.x; aAy += e4[i] * va4.y; aAz += e4[i] * va4.z; aAw += e4[i] * va4.w;
        aBx += e4[i] * vb4.x; aBy += e4[i] * vb4.y; aBz += e4[i] * vb4.z; aBw += e4[i] * vb4.w;
    }
    float* op = O + (size_t)r * DH + d0;
    float4 r0 = { aAx * inv, aAy * inv, aAz * inv, aAw * inv };
    float4 r1 = { aBx * inv, aBy * inv, aBz * inv, aBw * inv };
    *(float4*)op = r0;
    *(float4*)(op + 4) = r1;
}

// ============ kernels ============
__global__ void prep_k(const float* K, const float* V, ushort* Kb, ushort* Vb) {
    phase_prep(K, V, Kb, Vb, blockIdx.x, threadIdx.x);
}
__global__ __launch_bounds__(512, 2) void attn_k(const float* Q, const ushort* Kb, const ushort* Vb,
                                                 float* Opart, float* Ml) {
    phase_attn(Q, Kb, Vb, Opart, Ml, blockIdx.x, threadIdx.x);
}
__global__ void merge_k(const float* Opart, const float* Ml, float* O) {
    phase_merge(Opart, Ml, O, blockIdx.x, threadIdx.x);
}
__global__ __launch_bounds__(512, 2) void attn_coop_k(const float* Q, const float* K, const float* V,
                                                      ushort* Kb, ushort* Vb,
                                                      float* Opart, float* Ml, float* O) {
    const int bid = blockIdx.x, tid = threadIdx.x;
    phase_prep(K, V, Kb, Vb, bid, tid);
    cg::this_grid().sync();
    phase_attn(Q, Kb, Vb, Opart, Ml, bid, tid);
    cg::this_grid().sync();
    phase_merge(Opart, Ml, O, bid, tid);
}

// ================= round-4 fallback (ws >= 6MB) =================
#define KQ  2048
#define NTK (KQ / 64)

__global__ void conv_qk(const float* __restrict__ Q, const float* __restrict__ K,
                        ushort* __restrict__ Qb, ushort* __restrict__ Kb, int n4) {
    int idx = blockIdx.x * 256 + threadIdx.x;
    if (idx >= n4) return;
    float4 qv = ((const float4*)Q)[idx];
    float4 kv = ((const float4*)K)[idx];
    uint2 qo, ko;
    qo.x = f2bf(qv.x * 0.125f) | (f2bf(qv.y * 0.125f) << 16);
    qo.y = f2bf(qv.z * 0.125f) | (f2bf(qv.w * 0.125f) << 16);
    ko.x = f2bf(kv.x) | (f2bf(kv.y) << 16);
    ko.y = f2bf(kv.z) | (f2bf(kv.w) << 16);
    ((uint2*)Qb)[idx] = qo;
    ((uint2*)Kb)[idx] = ko;
}

__global__ void conv_vt(const float* __restrict__ V, ushort* __restrict__ Vt) {
    __shared__ ushort T[64][65];
    const int tid = threadIdx.x;
    const int s0 = blockIdx.x * 64, b = blockIdx.y;
    const float* base = V + ((size_t)b * SEQ + s0) * DH;
#pragma unroll
    for (int i = 0; i < 4; ++i) {
        int f4 = tid + 256 * i;
        int sl = f4 >> 4, d4 = (f4 & 15) * 4;
        float4 v = *(const float4*)(base + sl * DH + d4);
        T[d4 + 0][sl] = (ushort)f2bf(v.x);
        T[d4 + 1][sl] = (ushort)f2bf(v.y);
        T[d4 + 2][sl] = (ushort)f2bf(v.z);
        T[d4 + 3][sl] = (ushort)f2bf(v.w);
    }
    __syncthreads();
    ushort* outb = Vt + (size_t)b * DH * SEQ + s0;
#pragma unroll
    for (int i = 0; i < 8; ++i) {
        int u = tid + 256 * i;
        int d = u >> 5, s2 = (u & 31) * 2;
        uint pk = (uint)T[d][s2] | ((uint)T[d][s2 + 1] << 16);
        *(uint*)(outb + (size_t)d * SEQ + s2) = pk;
    }
}

__global__ __launch_bounds__(256, 2) void attn_fwd_reg(
    const ushort* __restrict__ Qb, const ushort* __restrict__ Kb,
    const ushort* __restrict__ Vt, float* __restrict__ O)
{
    __shared__ float Sp[4][64][33];
    __shared__ float Mlx[4][2][32];

    const int tid = threadIdx.x;
    const int lane = tid & 63;
    const int wid = tid >> 6;
    const int q = lane & 31;
    const int hi = lane >> 5;
    const int b = blockIdx.y;
    const int q0 = blockIdx.x * 32;

    const ushort* Qr = Qb + ((size_t)b * SEQ + q0 + q) * DH + 8 * hi;
    short8v qf[4];
#pragma unroll
    for (int t = 0; t < 4; ++t) qf[t] = *(const short8v*)(Qr + 16 * t);

    const ushort* Kl = Kb + ((size_t)b * SEQ + wid * KQ + q) * DH + 8 * hi;
    const ushort* Vl = Vt + ((size_t)b * DH + q) * SEQ + wid * KQ + 8 * hi;

    f32x16 o0, o1;
#pragma unroll
    for (int j = 0; j < 16; ++j) { o0[j] = 0.f; o1[j] = 0.f; }
    float m = -1e30f, l = 0.f;

    short8v ka[8];
#pragma unroll
    for (int kb = 0; kb < 2; ++kb)
#pragma unroll
        for (int t = 0; t < 4; ++t)
            ka[kb * 4 + t] = *(const short8v*)(Kl + (size_t)(kb * 32) * DH + 16 * t);

    for (int kt = 0; kt < NTK; ++kt) {
        const ushort* Vp = Vl + kt * 64;
        short8v va[8];
#pragma unroll
        for (int db = 0; db < 2; ++db)
#pragma unroll
            for (int kc = 0; kc < 4; ++kc)
                va[db * 4 + kc] = *(const short8v*)(Vp + (size_t)(db * 32) * SEQ + 16 * kc);

        f32x16 s0, s1;
#pragma unroll
        for (int j = 0; j < 16; ++j) { s0[j] = 0.f; s1[j] = 0.f; }
#pragma unroll
        for (int t = 0; t < 4; ++t) {
            s0 = __builtin_amdgcn_mfma_f32_32x32x16_bf16(ka[t],     qf[t], s0, 0, 0, 0);
            s1 = __builtin_amdgcn_mfma_f32_32x32x16_bf16(ka[4 + t], qf[t], s1, 0, 0, 0);
        }

        if (kt + 1 < NTK) {
            const ushort* Kn = Kl + (size_t)(kt + 1) * 64 * DH;
#pragma unroll
            for (int kb = 0; kb < 2; ++kb)
#pragma unroll
                for (int t = 0; t < 4; ++t)
                    ka[kb * 4 + t] = *(const short8v*)(Kn + (size_t)(kb * 32) * DH + 16 * t);
        }

        float tm;
        {
            f32x16 tv;
#pragma unroll
            for (int j = 0; j < 16; ++j) tv[j] = fmaxf(s0[j], s1[j]);
#pragma unroll
            for (int j = 0; j < 8; ++j) tv[j] = fmaxf(tv[j], tv[j + 8]);
#pragma unroll
            for (int j = 0; j < 4; ++j) tv[j] = fmaxf(tv[j], tv[j + 4]);
            tm = fmaxf(fmaxf(tv[0], tv[1]), fmaxf(tv[2], tv[3]));
        }
        tm = fmaxf(tm, __shfl_xor(tm, 32));
        float mnew = fmaxf(m, tm);
        if (__any(mnew > m)) {
            float sc = __expf(m - mnew);
            l *= sc;
#pragma unroll
            for (int j = 0; j < 16; ++j) { o0[j] *= sc; o1[j] *= sc; }
            m = mnew;
        }
#pragma unroll
        for (int j = 0; j < 16; ++j) {
            s0[j] = __expf(s0[j] - m);
            s1[j] = __expf(s1[j] - m);
        }
        {
            f32x16 pa;
#pragma unroll
            for (int j = 0; j < 16; ++j) pa[j] = s0[j] + s1[j];
#pragma unroll
            for (int j = 0; j < 8; ++j) pa[j] += pa[j + 8];
#pragma unroll
            for (int j = 0; j < 4; ++j) pa[j] += pa[j + 4];
            float ls = (pa[0] + pa[1]) + (pa[2] + pa[3]);
            ls += __shfl_xor(ls, 32);
            l += ls;
        }

        uint W[16];
#pragma unroll
        for (int i = 0; i < 8; ++i) {
#pragma unroll
            for (int c = 0; c < 2; ++c) {
                int kb3 = i >> 2, rg = ((i & 3) << 2) | (c << 1);
                float lo = kb3 ? s1[rg] : s0[rg];
                float hh = kb3 ? s1[rg + 1] : s0[rg + 1];
                uint ww;
                asm("v_cvt_pk_bf16_f32 %0, %1, %2" : "=v"(ww) : "v"(lo), "v"(hh));
                W[2 * i + c] = ww;
            }
        }
        short8v bfrag[4];
#pragma unroll
        for (int kc = 0; kc < 4; ++kc) {
            uint w0 = W[4 * kc], w1 = W[4 * kc + 1], w2 = W[4 * kc + 2], w3 = W[4 * kc + 3];
            uint y02 = hi ? w0 : w2;
            uint z02 = __shfl_xor(y02, 32);
            uint y13 = hi ? w1 : w3;
            uint z13 = __shfl_xor(y13, 32);
            union { uint u[4]; short8v v; } cv;
            cv.u[0] = hi ? z02 : w0;
            cv.u[1] = hi ? z13 : w1;
            cv.u[2] = hi ? w2 : z02;
            cv.u[3] = hi ? w3 : z13;
            bfrag[kc] = cv.v;
        }

#pragma unroll
        for (int kc = 0; kc < 4; ++kc) {
            o0 = __builtin_amdgcn_mfma_f32_32x32x16_bf16(va[kc],     bfrag[kc], o0, 0, 0, 0);
            o1 = __builtin_amdgcn_mfma_f32_32x32x16_bf16(va[4 + kc], bfrag[kc], o1, 0, 0, 0);
        }
    }

#pragma unroll
    for (int rg = 0; rg < 16; ++rg) {
        int d = (rg & 3) + 8 * (rg >> 2) + 4 * hi;
        Sp[wid][d][q]      = o0[rg];
        Sp[wid][d + 32][q] = o1[rg];
    }
    if (hi == 0) { Mlx[wid][0][q] = m; Mlx[wid][1][q] = l; }
    __syncthreads();

    float* Ob = O + ((size_t)b * SEQ + q0) * DH;
#pragma unroll
    for (int it = 0; it < 2; ++it) {
        int f4 = tid + 256 * it;
        int qq = f4 >> 4, d4 = (f4 & 15) * 4;
        float m0 = Mlx[0][0][qq], m1 = Mlx[1][0][qq], m2 = Mlx[2][0][qq], m3 = Mlx[3][0][qq];
        float ms = fmaxf(fmaxf(m0, m1), fmaxf(m2, m3));
        float e0 = __expf(m0 - ms), e1 = __expf(m1 - ms),
              e2 = __expf(m2 - ms), e3 = __expf(m3 - ms);
        float lt = Mlx[0][1][qq] * e0 + Mlx[1][1][qq] * e1 +
                   Mlx[2][1][qq] * e2 + Mlx[3][1][qq] * e3;
        float inv = 1.0f / lt;
        float4 r;
        r.x = (Sp[0][d4+0][qq]*e0 + Sp[1][d4+0][qq]*e1 + Sp[2][d4+0][qq]*e2 + Sp[3][d4+0][qq]*e3) * inv;
        r.y = (Sp[0][d4+1][qq]*e0 + Sp[1][d4+1][qq]*e1 + Sp[2][d4+1][qq]*e2 + Sp[3][d4+1][qq]*e3) * inv;
        r.z = (Sp[0][d4+2][qq]*e0 + Sp[1][d4+2][qq]*e1 + Sp[2][d4+2][qq]*e2 + Sp[3][d4+2][qq]*e3) * inv;
        r.w = (Sp[0][d4+3][qq]*e0 + Sp[1][d4+3][qq]*e1 + Sp[2][d4+3][qq]*e2 + Sp[3][d4+3][qq]*e3) * inv;
        *(float4*)(Ob + (size_t)qq * DH + d4) = r;
    }
}

// ================= round-3 fallback (no ws) =================
#define BQ  64
#define BK  64
#define NT  (SEQ / 2 / BK)
#define OFF_K 0
#define OFF_V 16384
#define OFF_P 32768
#define LDS_BYTES 49152

__device__ __forceinline__ ushort f2bfs(float f) {
    uint u = __float_as_uint(f);
    return (ushort)((u + 0x7FFFu + ((u >> 16) & 1u)) >> 16);
}
__device__ __forceinline__ uint swz(uint row, uint colByte) {
    return row * 128u + (colByte ^ ((row & 7u) << 4));
}

__global__ __launch_bounds__(512, 2) void attn_fwd_mfma(
    const float* __restrict__ Q, const float* __restrict__ K,
    const float* __restrict__ V, float* __restrict__ O)
{
    __shared__ ulong2 smem_[LDS_BYTES / 16];
    char* smem = (char*)smem_;
    const int tid = threadIdx.x;
    const int lane = tid & 63;
    const int wid = tid >> 6;
    const int grp = wid >> 2;
    const int w = wid & 3;
    const int l15 = lane & 15;
    const int l4 = lane >> 4;
    const int batch = blockIdx.y;
    const int q0 = blockIdx.x * BQ;
    const int m0 = w * 16;
    const float* Qb = Q + ((size_t)batch * SEQ + q0) * DH;
    const float* Kb = K + ((size_t)batch * SEQ + (size_t)grp * (SEQ / 2)) * DH;
    const float* Vb = V + ((size_t)batch * SEQ + (size_t)grp * (SEQ / 2)) * DH;
    short8v qf[2];
    {
        const float* qr = Qb + (m0 + l15) * DH;
#pragma unroll
        for (int t = 0; t < 2; ++t) {
            float4 a = *(const float4*)(qr + t * 32 + l4 * 8);
            float4 bb = *(const float4*)(qr + t * 32 + l4 * 8 + 4);
            short8v v;
            v[0] = (short)f2bfs(a.x * 0.125f); v[1] = (short)f2bfs(a.y * 0.125f);
            v[2] = (short)f2bfs(a.z * 0.125f); v[3] = (short)f2bfs(a.w * 0.125f);
            v[4] = (short)f2bfs(bb.x * 0.125f); v[5] = (short)f2bfs(bb.y * 0.125f);
            v[6] = (short)f2bfs(bb.z * 0.125f); v[7] = (short)f2bfs(bb.w * 0.125f);
            qf[t] = v;
        }
    }
    const int tg = tid & 255;
    const int k2 = tg & 31;
    const int dq0 = tg >> 5;
    char* kb = smem + OFF_K + grp * 8192;
    char* vb = smem + OFF_V + grp * 8192;
    char* pb = smem + OFF_P + wid * 2048;
    float4 kp[4], vp[4];
    auto issue = [&](int kt) {
        const float* Kt = Kb + (size_t)kt * BK * DH;
        const float* Vtp = Vb + (size_t)kt * BK * DH;
#pragma unroll
        for (int i = 0; i < 4; ++i) kp[i] = ((const float4*)Kt)[tg + 256 * i];
#pragma unroll
        for (int dd = 0; dd < 2; ++dd) {
            int dq = dq0 + 8 * dd;
            vp[2 * dd] = *(const float4*)(Vtp + (2 * k2) * DH + 4 * dq);
            vp[2 * dd + 1] = *(const float4*)(Vtp + (2 * k2 + 1) * DH + 4 * dq);
        }
    };
    auto stash = [&]() {
#pragma unroll
        for (int i = 0; i < 4; ++i) {
            int f = tg + 256 * i;
            uint row = (uint)(f >> 4), c4 = (uint)(f & 15);
            uint2 h;
            h.x = (uint)f2bfs(kp[i].x) | ((uint)f2bfs(kp[i].y) << 16);
            h.y = (uint)f2bfs(kp[i].z) | ((uint)f2bfs(kp[i].w) << 16);
            *(uint2*)(kb + swz(row, c4 * 8)) = h;
        }
#pragma unroll
        for (int dd = 0; dd < 2; ++dd) {
            int dq = dq0 + 8 * dd;
            float a0[4] = {vp[2*dd].x, vp[2*dd].y, vp[2*dd].z, vp[2*dd].w};
            float a1[4] = {vp[2*dd+1].x, vp[2*dd+1].y, vp[2*dd+1].z, vp[2*dd+1].w};
#pragma unroll
            for (int e = 0; e < 4; ++e) {
                uint pk = (uint)f2bfs(a0[e]) | ((uint)f2bfs(a1[e]) << 16);
                *(uint*)(vb + swz((uint)(4 * dq + e), (uint)(4 * k2))) = pk;
            }
        }
    };
    f32x4 o[4];
#pragma unroll
    for (int j = 0; j < 4; ++j) o[j] = (f32x4){0.f, 0.f, 0.f, 0.f};
    float mrow[4] = {-1e30f, -1e30f, -1e30f, -1e30f};
    float lrow[4] = {0.f, 0.f, 0.f, 0.f};
    issue(0);
    stash();
    __syncthreads();
    for (int kt = 0; kt < NT; ++kt) {
        if (kt + 1 < NT) issue(kt + 1);
        f32x4 s[4];
#pragma unroll
        for (int j = 0; j < 4; ++j) s[j] = (f32x4){0.f, 0.f, 0.f, 0.f};
#pragma unroll
        for (int t = 0; t < 2; ++t) {
#pragma unroll
            for (int j = 0; j < 4; ++j) {
                short8v kf = *(const short8v*)(kb + swz((uint)(j * 16 + l15),
                                                        (uint)(t * 64 + l4 * 16)));
                s[j] = __builtin_amdgcn_mfma_f32_16x16x32_bf16(qf[t], kf, s[j], 0, 0, 0);
            }
        }
#pragma unroll
        for (int r = 0; r < 4; ++r) {
            float tm = fmaxf(fmaxf(s[0][r], s[1][r]), fmaxf(s[2][r], s[3][r]));
            tm = fmaxf(tm, __shfl_xor(tm, 1));
            tm = fmaxf(tm, __shfl_xor(tm, 2));
            tm = fmaxf(tm, __shfl_xor(tm, 4));
            tm = fmaxf(tm, __shfl_xor(tm, 8));
            float mn = fmaxf(mrow[r], tm);
            float sc = __expf(mrow[r] - mn);
            mrow[r] = mn;
            float p0 = __expf(s[0][r] - mn);
            float p1 = __expf(s[1][r] - mn);
            float p2 = __expf(s[2][r] - mn);
            float p3 = __expf(s[3][r] - mn);
            float ls = (p0 + p1) + (p2 + p3);
            ls += __shfl_xor(ls, 1);
            ls += __shfl_xor(ls, 2);
            ls += __shfl_xor(ls, 4);
            ls += __shfl_xor(ls, 8);
            lrow[r] = lrow[r] * sc + ls;
            o[0][r] *= sc; o[1][r] *= sc; o[2][r] *= sc; o[3][r] *= sc;
            uint rowb = (uint)(l4 * 4 + r);
            *(ushort*)(pb + swz(rowb, (uint)((0 * 16 + l15) * 2))) = f2bfs(p0);
            *(ushort*)(pb + swz(rowb, (uint)((1 * 16 + l15) * 2))) = f2bfs(p1);
            *(ushort*)(pb + swz(rowb, (uint)((2 * 16 + l15) * 2))) = f2bfs(p2);
            *(ushort*)(pb + swz(rowb, (uint)((3 * 16 + l15) * 2))) = f2bfs(p3);
        }
        short8v pf[2];
#pragma unroll
        for (int t = 0; t < 2; ++t)
            pf[t] = *(const short8v*)(pb + swz((uint)l15, (uint)(t * 64 + l4 * 16)));
#pragma unroll
        for (int t = 0; t < 2; ++t) {
#pragma unroll
            for (int j = 0; j < 4; ++j) {
                short8v vf = *(const short8v*)(vb + swz((uint)(j * 16 + l15),
                                                        (uint)(t * 64 + l4 * 16)));
                o[j] = __builtin_amdgcn_mfma_f32_16x16x32_bf16(pf[t], vf, o[j], 0, 0, 0);
            }
        }
        __syncthreads();
        if (kt + 1 < NT) stash();
        __syncthreads();
    }
    float* A0 = (float*)smem;
    float* M0 = (float*)(smem + 20480);
    float* L0 = (float*)(smem + 20736);
    if (grp == 0) {
#pragma unroll
        for (int r = 0; r < 4; ++r) {
            uint rowA = (uint)(m0 + l4 * 4 + r);
#pragma unroll
            for (int j = 0; j < 4; ++j)
                A0[rowA * 68 + j * 16 + l15] = o[j][r];
            if (l15 == 0) { M0[rowA] = mrow[r]; L0[rowA] = lrow[r]; }
        }
    }
    __syncthreads();
    if (grp == 1) {
        float* Ob = O + ((size_t)batch * SEQ + q0) * DH;
#pragma unroll
        for (int r = 0; r < 4; ++r) {
            uint rowA = (uint)(m0 + l4 * 4 + r);
            float m1 = mrow[r], l1 = lrow[r];
            float m0r = M0[rowA], l0r = L0[rowA];
            float mn = fmaxf(m0r, m1);
            float s0 = __expf(m0r - mn), s1 = __expf(m1 - mn);
            float inv = 1.0f / (l0r * s0 + l1 * s1);
#pragma unroll
            for (int j = 0; j < 4; ++j) {
                float af = A0[rowA * 68 + j * 16 + l15] * s0 + o[j][r] * s1;
                Ob[rowA * DH + j * 16 + l15] = af * inv;
            }
        }
    }
}

// ============ launcher ============
extern "C" void kernel_launch(void* const* d_in, const int* in_sizes, int n_in,
                              void* d_out, int out_size, void* d_ws, size_t ws_size,
                              hipStream_t stream) {
    (void)n_in; (void)out_size;
    const float* x1 = (const float*)d_in[0];
    const float* x2 = (const float*)d_in[1];
    const float* x3 = (const float*)d_in[2];
    float* out = (float*)d_out;
    const int B = in_sizes[0] / (SEQ * DH);
    const size_t tsz = (size_t)B * SEQ * DH * sizeof(ushort);

    if (B == 2 && ws_size >= WS_NEED) {
        ushort* Kb = (ushort*)d_ws;
        ushort* Vb = (ushort*)((char*)d_ws + WS_VB);
        float* Opart = (float*)((char*)d_ws + WS_OP);
        float* Mlp = (float*)((char*)d_ws + WS_ML);
        void* args[] = { (void*)&x1, (void*)&x2, (void*)&x3,
                         (void*)&Kb, (void*)&Vb, (void*)&Opart, (void*)&Mlp, (void*)&out };
        hipError_t e = hipLaunchCooperativeKernel((const void*)attn_coop_k,
                                                  dim3(256), dim3(512), args, 0, stream);
        if (e != hipSuccess) {
            prep_k<<<256, 512, 0, stream>>>(x2, x3, Kb, Vb);
            attn_k<<<256, 512, 0, stream>>>(x1, Kb, Vb, Opart, Mlp);
            merge_k<<<256, 512, 0, stream>>>(Opart, Mlp, out);
        }
    } else if (ws_size >= 3 * tsz) {
        ushort* Qb = (ushort*)d_ws;
        ushort* Kb = (ushort*)((char*)d_ws + tsz);
        ushort* Vtp = (ushort*)((char*)d_ws + 2 * tsz);
        int n4 = B * SEQ * DH / 4;
        conv_qk<<<(n4 + 255) / 256, 256, 0, stream>>>(x1, x2, Qb, Kb, n4);
        conv_vt<<<dim3(SEQ / 64, B), 256, 0, stream>>>(x3, Vtp);
        attn_fwd_reg<<<dim3(SEQ / 32, B), 256, 0, stream>>>(Qb, Kb, Vtp, out);
    } else {
        attn_fwd_mfma<<<dim3(SEQ / BQ, B), 512, 0, stream>>>(x1, x2, x3, out);
    }
}

// Round 9
// 126.996 us; speedup vs baseline: 1.6576x; 1.6576x over previous
//
#include <hip/hip_runtime.h>

// Flash attention fwd, B=2 S=8192 D=64. Round 7 (resubmit after 2x broker timeout).
// prep: K -> bf16 Kb[b][s][d]; V -> bf16 TRANSPOSED Vt[b][d][s].
// attn: 512 blocks x 256 thr (4 waves). Block = (b, quarter, qt): 128 q-rows,
//       2048-key quarter (split-K=4). K and V tiles both staged to LDS with
//       conflict-free swizzled ds_write_b128 (V now row-major from Vt).
//       2 blocks/CU -> independent barrier domains. setprio around MFMA.
// merge: 4-way split-K merge.
// Fragment/softmax/exchange math identical to rounds 4-6 (absmax 7.3e-4).

#define SEQ 8192
#define DH  64

typedef __attribute__((ext_vector_type(8)))  short short8v;
typedef __attribute__((ext_vector_type(4)))  float f32x4;
typedef __attribute__((ext_vector_type(16))) float f32x16;

__device__ __forceinline__ uint f2bf(float f) {
    uint u = __float_as_uint(f);
    return (u + 0x7FFFu + ((u >> 16) & 1u)) >> 16;  // RNE
}

// ws layout: Kb 2MB | Vt 2MB | Opart 16.78MB | Ml 0.5MB  = 21,495,808 B
#define WS_VT 2097152
#define WS_OP 4194304
#define WS_ML 20971520
#define WS_NEED 21495808ULL

// ============ prep: K convert + V transpose-convert ============
__global__ __launch_bounds__(256) void prep_k2(const float* __restrict__ K,
                                               const float* __restrict__ V,
                                               ushort* __restrict__ Kb,
                                               ushort* __restrict__ Vt) {
    const int bid = blockIdx.x, tid = threadIdx.x;
    if (bid < 256) {
        // V transpose: tile = 64 keys x 64 d. b = bid>>7, s0 = (bid&127)*64.
        __shared__ ushort T[64][65];
        const int b = bid >> 7, s0 = (bid & 127) * 64;
        const float* base = V + ((size_t)b * SEQ + s0) * DH;
#pragma unroll
        for (int i = 0; i < 4; ++i) {
            int f4 = tid + 256 * i;
            int sl = f4 >> 4, d4 = (f4 & 15) * 4;
            float4 v = *(const float4*)(base + sl * DH + d4);
            T[d4 + 0][sl] = (ushort)f2bf(v.x);
            T[d4 + 1][sl] = (ushort)f2bf(v.y);
            T[d4 + 2][sl] = (ushort)f2bf(v.z);
            T[d4 + 3][sl] = (ushort)f2bf(v.w);
        }
        __syncthreads();
        ushort* outb = Vt + (size_t)b * DH * SEQ + s0;
#pragma unroll
        for (int i = 0; i < 8; ++i) {
            int u = tid + 256 * i;
            int d = u >> 5, s2 = (u & 31) * 2;
            uint pk = (uint)T[d][s2] | ((uint)T[d][s2 + 1] << 16);
            *(uint*)(outb + (size_t)d * SEQ + s2) = pk;
        }
    } else {
        // K convert: 1M f32, 65536 threads x 16 elems
        size_t base = ((size_t)(bid - 256) * 256 + tid) * 16;
#pragma unroll
        for (int h = 0; h < 2; ++h) {
            float4 a = *(const float4*)(K + base + 8 * h);
            float4 c = *(const float4*)(K + base + 8 * h + 4);
            uint4 ko;
            ko.x = f2bf(a.x) | (f2bf(a.y) << 16);
            ko.y = f2bf(a.z) | (f2bf(a.w) << 16);
            ko.z = f2bf(c.x) | (f2bf(c.y) << 16);
            ko.w = f2bf(c.z) | (f2bf(c.w) << 16);
            *(uint4*)(Kb + base + 8 * h) = ko;
        }
    }
}

// ============ attn: 512 blocks x 256 threads ============
__global__ __launch_bounds__(256, 2) void attn_k2(const float* __restrict__ Q,
                                                  const ushort* __restrict__ Kb,
                                                  const ushort* __restrict__ Vt,
                                                  float* __restrict__ Opart,
                                                  float* __restrict__ Ml) {
    __shared__ __align__(16) char smem[32768];  // 2 x (K 8KB + V 8KB)

    const int bid = blockIdx.x, tid = threadIdx.x;
    const int wk = (bid & 7) * 64 + (bid >> 3);       // XCD swizzle (512 % 8 == 0)
    const int qt = wk & 63, quarter = (wk >> 6) & 3, b = wk >> 8;
    const int q0 = qt * 128, kq0 = quarter * 2048;
    const int lane = tid & 63, w = tid >> 6;          // 4 waves, 32 q-rows each
    const int q = lane & 31, hi = lane >> 5;

    // ---- Q fragments (x0.125 folded) ----
    short8v qf[4];
    {
        const float* qr = Q + ((size_t)b * SEQ + q0 + 32 * w + q) * DH + 8 * hi;
#pragma unroll
        for (int t = 0; t < 4; ++t) {
            float4 a = *(const float4*)(qr + 16 * t);
            float4 c = *(const float4*)(qr + 16 * t + 4);
            union { uint u[4]; short8v v; } cv;
            cv.u[0] = f2bf(a.x * 0.125f) | (f2bf(a.y * 0.125f) << 16);
            cv.u[1] = f2bf(a.z * 0.125f) | (f2bf(a.w * 0.125f) << 16);
            cv.u[2] = f2bf(c.x * 0.125f) | (f2bf(c.y * 0.125f) << 16);
            cv.u[3] = f2bf(c.z * 0.125f) | (f2bf(c.w * 0.125f) << 16);
            qf[t] = cv.v;
        }
    }

    // ---- staging: K slots (skey,ocho), V slots (d,ko); 2 slots each ----
    const int skey = tid >> 3, ocho = tid & 7;        // K: key row, 8-elem chunk
    const ushort* Ks0 = Kb + ((size_t)b * SEQ + kq0 + skey) * DH + 8 * ocho;
    const ushort* Ks1 = Ks0 + (size_t)32 * DH;        // skey+32
    const ushort* Vs0 = Vt + ((size_t)b * DH + skey) * SEQ + kq0 + 8 * ocho;   // d=skey
    const ushort* Vs1 = Vs0 + (size_t)32 * SEQ;       // d+32

    short8v kr0, kr1, vr0, vr1;
    auto stage_load = [&](int kt) {
        kr0 = *(const short8v*)(Ks0 + (size_t)kt * 64 * DH);
        kr1 = *(const short8v*)(Ks1 + (size_t)kt * 64 * DH);
        vr0 = *(const short8v*)(Vs0 + kt * 64);
        vr1 = *(const short8v*)(Vs1 + kt * 64);
    };
    const uint kslot = (uint)((ocho ^ (skey & 7)) << 4);
    auto stage_write = [&](int p) {
        char* kbp = smem + p * 16384;
        char* vbp = kbp + 8192;
        *(short8v*)(kbp + skey * 128 + kslot) = kr0;
        *(short8v*)(kbp + (skey + 32) * 128 + kslot) = kr1;   // (skey+32)&7 == skey&7
        *(short8v*)(vbp + skey * 128 + kslot) = vr0;
        *(short8v*)(vbp + (skey + 32) * 128 + kslot) = vr1;
    };

    f32x16 o0, o1;
#pragma unroll
    for (int j = 0; j < 16; ++j) { o0[j] = 0.f; o1[j] = 0.f; }
    float m = -1e30f, l = 0.f;

    stage_load(0); stage_write(0); __syncthreads();

    for (int kt = 0; kt < 32; ++kt) {
        const int p = kt & 1;
        if (kt + 1 < 32) stage_load(kt + 1);
        char* kbp = smem + p * 16384;
        char* vbp = kbp + 8192;

        // ---- K fragments + S^T = K Q^T ----
        short8v ka[8];
#pragma unroll
        for (int kb2 = 0; kb2 < 2; ++kb2)
#pragma unroll
            for (int t = 0; t < 4; ++t) {
                int row = kb2 * 32 + q;
                ka[kb2 * 4 + t] = *(const short8v*)(kbp + row * 128 + (((2 * t + hi) ^ (row & 7)) << 4));
            }
        f32x16 s0, s1;
#pragma unroll
        for (int j = 0; j < 16; ++j) { s0[j] = 0.f; s1[j] = 0.f; }
        __builtin_amdgcn_s_setprio(1);
#pragma unroll
        for (int t = 0; t < 4; ++t) {
            s0 = __builtin_amdgcn_mfma_f32_32x32x16_bf16(ka[t],     qf[t], s0, 0, 0, 0);
            s1 = __builtin_amdgcn_mfma_f32_32x32x16_bf16(ka[4 + t], qf[t], s1, 0, 0, 0);
        }
        __builtin_amdgcn_s_setprio(0);

        // ---- online softmax (lane owns q-row; verified r4-r6) ----
        float tm;
        {
            f32x16 tv;
#pragma unroll
            for (int j = 0; j < 16; ++j) tv[j] = fmaxf(s0[j], s1[j]);
#pragma unroll
            for (int j = 0; j < 8; ++j) tv[j] = fmaxf(tv[j], tv[j + 8]);
#pragma unroll
            for (int j = 0; j < 4; ++j) tv[j] = fmaxf(tv[j], tv[j + 4]);
            tm = fmaxf(fmaxf(tv[0], tv[1]), fmaxf(tv[2], tv[3]));
        }
        tm = fmaxf(tm, __shfl_xor(tm, 32));
        float mnew = fmaxf(m, tm);
        if (__any(mnew > m)) {
            float sc = __expf(m - mnew);
            l *= sc;
#pragma unroll
            for (int j = 0; j < 16; ++j) { o0[j] *= sc; o1[j] *= sc; }
            m = mnew;
        }
#pragma unroll
        for (int j = 0; j < 16; ++j) {
            s0[j] = __expf(s0[j] - m);
            s1[j] = __expf(s1[j] - m);
        }
        {
            f32x16 pa;
#pragma unroll
            for (int j = 0; j < 16; ++j) pa[j] = s0[j] + s1[j];
#pragma unroll
            for (int j = 0; j < 8; ++j) pa[j] += pa[j + 8];
#pragma unroll
            for (int j = 0; j < 4; ++j) pa[j] += pa[j + 4];
            float ls = (pa[0] + pa[1]) + (pa[2] + pa[3]);
            ls += __shfl_xor(ls, 32);
            l += ls;
        }

        // ---- pack P -> bf16 words + cross-half exchange -> B-frags ----
        uint W[16];
#pragma unroll
        for (int i = 0; i < 8; ++i) {
#pragma unroll
            for (int c = 0; c < 2; ++c) {
                int kb3 = i >> 2, rg = ((i & 3) << 2) | (c << 1);
                float lo = kb3 ? s1[rg] : s0[rg];
                float hh = kb3 ? s1[rg + 1] : s0[rg + 1];
                uint ww;
                asm("v_cvt_pk_bf16_f32 %0, %1, %2" : "=v"(ww) : "v"(lo), "v"(hh));
                W[2 * i + c] = ww;
            }
        }
        short8v bfrag[4];
#pragma unroll
        for (int kc = 0; kc < 4; ++kc) {
            uint w0 = W[4 * kc], w1 = W[4 * kc + 1], w2 = W[4 * kc + 2], w3 = W[4 * kc + 3];
            uint y02 = hi ? w0 : w2;
            uint z02 = __shfl_xor(y02, 32);
            uint y13 = hi ? w1 : w3;
            uint z13 = __shfl_xor(y13, 32);
            union { uint u[4]; short8v v; } cv;
            cv.u[0] = hi ? z02 : w0;
            cv.u[1] = hi ? z13 : w1;
            cv.u[2] = hi ? w2 : z02;
            cv.u[3] = hi ? w3 : z13;
            bfrag[kc] = cv.v;
        }

        // ---- V fragments (row-major Vt tile, same swizzle as K) + O^T += V^T P^T ----
        short8v va[8];
#pragma unroll
        for (int db = 0; db < 2; ++db)
#pragma unroll
            for (int kc = 0; kc < 4; ++kc) {
                int row = db * 32 + q;
                va[db * 4 + kc] = *(const short8v*)(vbp + row * 128 + (((2 * kc + hi) ^ (row & 7)) << 4));
            }
        __builtin_amdgcn_s_setprio(1);
#pragma unroll
        for (int kc = 0; kc < 4; ++kc) {
            o0 = __builtin_amdgcn_mfma_f32_32x32x16_bf16(va[kc],     bfrag[kc], o0, 0, 0, 0);
            o1 = __builtin_amdgcn_mfma_f32_32x32x16_bf16(va[4 + kc], bfrag[kc], o1, 0, 0, 0);
        }
        __builtin_amdgcn_s_setprio(0);

        if (kt + 1 < 32) stage_write((kt + 1) & 1);
        __syncthreads();
    }

    // ---- epilogue: coalesced partial stores in C-fragment layout ----
    float* Op = Opart + ((((size_t)quarter * 2 + b) * 64 + qt) * 4 + w) * 2048;
#pragma unroll
    for (int j = 0; j < 4; ++j) {
        f32x4 t0 = { o0[4 * j], o0[4 * j + 1], o0[4 * j + 2], o0[4 * j + 3] };
        *(f32x4*)(Op + j * 256 + lane * 4) = t0;
        f32x4 t1 = { o1[4 * j], o1[4 * j + 1], o1[4 * j + 2], o1[4 * j + 3] };
        *(f32x4*)(Op + (4 + j) * 256 + lane * 4) = t1;
    }
    if (hi == 0) {
        float2 v2 = make_float2(m, l);
        *(float2*)(Ml + ((size_t)quarter * 16384 + (size_t)b * 8192 + q0 + 32 * w + q) * 2) = v2;
    }
}

// ============ merge: 4 partials ============
__global__ __launch_bounds__(256) void merge_k2(const float* __restrict__ Opart,
                                                const float* __restrict__ Ml,
                                                float* __restrict__ O) {
    int g = blockIdx.x * 256 + threadIdx.x;   // 131072 = 16384 rows x 8 d-chunks
    int r = g >> 3, d0 = (g & 7) * 8;
    int bb = r >> 13, row = r & 8191;
    int qt = row >> 7, w = (row >> 5) & 3, q = row & 31;
    float mi[4], li[4];
#pragma unroll
    for (int i = 0; i < 4; ++i) {
        float2 v2 = *(const float2*)(Ml + ((size_t)i * 16384 + r) * 2);
        mi[i] = v2.x; li[i] = v2.y;
    }
    float M = fmaxf(fmaxf(mi[0], mi[1]), fmaxf(mi[2], mi[3]));
    float e4[4]; float lsum = 0.f;
#pragma unroll
    for (int i = 0; i < 4; ++i) { e4[i] = __expf(mi[i] - M); lsum += e4[i] * li[i]; }
    float inv = 1.0f / lsum;
    float aAx = 0, aAy = 0, aAz = 0, aAw = 0, aBx = 0, aBy = 0, aBz = 0, aBw = 0;
    const int oh = (d0 >= 32) ? 4 : 0;
    const int s8 = (d0 & 31) >> 3;
#pragma unroll
    for (int i = 0; i < 4; ++i) {
        size_t wb = ((((size_t)i * 2 + bb) * 64 + qt) * 4 + w) * 2048;
        const float* pa = Opart + wb + (size_t)(oh + s8) * 256 + q * 4;
        const float* pb = Opart + wb + (size_t)(oh + s8) * 256 + (q + 32) * 4;
        float4 va4 = *(const float4*)pa;
        float4 vb4 = *(const float4*)pb;
        aAx += e4[i] * va4.x; aAy += e4[i] * va4.y; aAz += e4[i] * va4.z; aAw += e4[i] * va4.w;
        aBx += e4[i] * vb4.x; aBy += e4[i] * vb4.y; aBz += e4[i] * vb4.z; aBw += e4[i] * vb4.w;
    }
    float* op = O + (size_t)r * DH + d0;
    float4 r0 = { aAx * inv, aAy * inv, aAz * inv, aAw * inv };
    float4 r1 = { aBx * inv, aBy * inv, aBz * inv, aBw * inv };
    *(float4*)op = r0;
    *(float4*)(op + 4) = r1;
}

// ================= round-3 fallback (no ws) =================
#define BQ  64
#define BK  64
#define NT  (SEQ / 2 / BK)
#define OFF_K 0
#define OFF_V 16384
#define OFF_P 32768
#define LDS_BYTES 49152

__device__ __forceinline__ ushort f2bfs(float f) {
    uint u = __float_as_uint(f);
    return (ushort)((u + 0x7FFFu + ((u >> 16) & 1u)) >> 16);
}
__device__ __forceinline__ uint swz(uint row, uint colByte) {
    return row * 128u + (colByte ^ ((row & 7u) << 4));
}

__global__ __launch_bounds__(512, 2) void attn_fwd_mfma(
    const float* __restrict__ Q, const float* __restrict__ K,
    const float* __restrict__ V, float* __restrict__ O)
{
    __shared__ ulong2 smem_[LDS_BYTES / 16];
    char* smem = (char*)smem_;
    const int tid = threadIdx.x;
    const int lane = tid & 63;
    const int wid = tid >> 6;
    const int grp = wid >> 2;
    const int w = wid & 3;
    const int l15 = lane & 15;
    const int l4 = lane >> 4;
    const int batch = blockIdx.y;
    const int q0 = blockIdx.x * BQ;
    const int m0 = w * 16;
    const float* Qb = Q + ((size_t)batch * SEQ + q0) * DH;
    const float* Kb = K + ((size_t)batch * SEQ + (size_t)grp * (SEQ / 2)) * DH;
    const float* Vb = V + ((size_t)batch * SEQ + (size_t)grp * (SEQ / 2)) * DH;
    short8v qf[2];
    {
        const float* qr = Qb + (m0 + l15) * DH;
#pragma unroll
        for (int t = 0; t < 2; ++t) {
            float4 a = *(const float4*)(qr + t * 32 + l4 * 8);
            float4 bb = *(const float4*)(qr + t * 32 + l4 * 8 + 4);
            short8v v;
            v[0] = (short)f2bfs(a.x * 0.125f); v[1] = (short)f2bfs(a.y * 0.125f);
            v[2] = (short)f2bfs(a.z * 0.125f); v[3] = (short)f2bfs(a.w * 0.125f);
            v[4] = (short)f2bfs(bb.x * 0.125f); v[5] = (short)f2bfs(bb.y * 0.125f);
            v[6] = (short)f2bfs(bb.z * 0.125f); v[7] = (short)f2bfs(bb.w * 0.125f);
            qf[t] = v;
        }
    }
    const int tg = tid & 255;
    const int k2 = tg & 31;
    const int dq0 = tg >> 5;
    char* kb = smem + OFF_K + grp * 8192;
    char* vb = smem + OFF_V + grp * 8192;
    char* pb = smem + OFF_P + wid * 2048;
    float4 kp[4], vp[4];
    auto issue = [&](int kt) {
        const float* Kt = Kb + (size_t)kt * BK * DH;
        const float* Vtp = Vb + (size_t)kt * BK * DH;
#pragma unroll
        for (int i = 0; i < 4; ++i) kp[i] = ((const float4*)Kt)[tg + 256 * i];
#pragma unroll
        for (int dd = 0; dd < 2; ++dd) {
            int dq = dq0 + 8 * dd;
            vp[2 * dd] = *(const float4*)(Vtp + (2 * k2) * DH + 4 * dq);
            vp[2 * dd + 1] = *(const float4*)(Vtp + (2 * k2 + 1) * DH + 4 * dq);
        }
    };
    auto stash = [&]() {
#pragma unroll
        for (int i = 0; i < 4; ++i) {
            int f = tg + 256 * i;
            uint row = (uint)(f >> 4), c4 = (uint)(f & 15);
            uint2 h;
            h.x = (uint)f2bfs(kp[i].x) | ((uint)f2bfs(kp[i].y) << 16);
            h.y = (uint)f2bfs(kp[i].z) | ((uint)f2bfs(kp[i].w) << 16);
            *(uint2*)(kb + swz(row, c4 * 8)) = h;
        }
#pragma unroll
        for (int dd = 0; dd < 2; ++dd) {
            int dq = dq0 + 8 * dd;
            float a0[4] = {vp[2*dd].x, vp[2*dd].y, vp[2*dd].z, vp[2*dd].w};
            float a1[4] = {vp[2*dd+1].x, vp[2*dd+1].y, vp[2*dd+1].z, vp[2*dd+1].w};
#pragma unroll
            for (int e = 0; e < 4; ++e) {
                uint pk = (uint)f2bfs(a0[e]) | ((uint)f2bfs(a1[e]) << 16);
                *(uint*)(vb + swz((uint)(4 * dq + e), (uint)(4 * k2))) = pk;
            }
        }
    };
    f32x4 o[4];
#pragma unroll
    for (int j = 0; j < 4; ++j) o[j] = (f32x4){0.f, 0.f, 0.f, 0.f};
    float mrow[4] = {-1e30f, -1e30f, -1e30f, -1e30f};
    float lrow[4] = {0.f, 0.f, 0.f, 0.f};
    issue(0);
    stash();
    __syncthreads();
    for (int kt = 0; kt < NT; ++kt) {
        if (kt + 1 < NT) issue(kt + 1);
        f32x4 s[4];
#pragma unroll
        for (int j = 0; j < 4; ++j) s[j] = (f32x4){0.f, 0.f, 0.f, 0.f};
#pragma unroll
        for (int t = 0; t < 2; ++t) {
#pragma unroll
            for (int j = 0; j < 4; ++j) {
                short8v kf = *(const short8v*)(kb + swz((uint)(j * 16 + l15),
                                                        (uint)(t * 64 + l4 * 16)));
                s[j] = __builtin_amdgcn_mfma_f32_16x16x32_bf16(qf[t], kf, s[j], 0, 0, 0);
            }
        }
#pragma unroll
        for (int r = 0; r < 4; ++r) {
            float tm = fmaxf(fmaxf(s[0][r], s[1][r]), fmaxf(s[2][r], s[3][r]));
            tm = fmaxf(tm, __shfl_xor(tm, 1));
            tm = fmaxf(tm, __shfl_xor(tm, 2));
            tm = fmaxf(tm, __shfl_xor(tm, 4));
            tm = fmaxf(tm, __shfl_xor(tm, 8));
            float mn = fmaxf(mrow[r], tm);
            float sc = __expf(mrow[r] - mn);
            mrow[r] = mn;
            float p0 = __expf(s[0][r] - mn);
            float p1 = __expf(s[1][r] - mn);
            float p2 = __expf(s[2][r] - mn);
            float p3 = __expf(s[3][r] - mn);
            float ls = (p0 + p1) + (p2 + p3);
            ls += __shfl_xor(ls, 1);
            ls += __shfl_xor(ls, 2);
            ls += __shfl_xor(ls, 4);
            ls += __shfl_xor(ls, 8);
            lrow[r] = lrow[r] * sc + ls;
            o[0][r] *= sc; o[1][r] *= sc; o[2][r] *= sc; o[3][r] *= sc;
            uint rowb = (uint)(l4 * 4 + r);
            *(ushort*)(pb + swz(rowb, (uint)((0 * 16 + l15) * 2))) = f2bfs(p0);
            *(ushort*)(pb + swz(rowb, (uint)((1 * 16 + l15) * 2))) = f2bfs(p1);
            *(ushort*)(pb + swz(rowb, (uint)((2 * 16 + l15) * 2))) = f2bfs(p2);
            *(ushort*)(pb + swz(rowb, (uint)((3 * 16 + l15) * 2))) = f2bfs(p3);
        }
        short8v pf[2];
#pragma unroll
        for (int t = 0; t < 2; ++t)
            pf[t] = *(const short8v*)(pb + swz((uint)l15, (uint)(t * 64 + l4 * 16)));
#pragma unroll
        for (int t = 0; t < 2; ++t) {
#pragma unroll
            for (int j = 0; j < 4; ++j) {
                short8v vf = *(const short8v*)(vb + swz((uint)(j * 16 + l15),
                                                        (uint)(t * 64 + l4 * 16)));
                o[j] = __builtin_amdgcn_mfma_f32_16x16x32_bf16(pf[t], vf, o[j], 0, 0, 0);
            }
        }
        __syncthreads();
        if (kt + 1 < NT) stash();
        __syncthreads();
    }
    float* A0 = (float*)smem;
    float* M0 = (float*)(smem + 20480);
    float* L0 = (float*)(smem + 20736);
    if (grp == 0) {
#pragma unroll
        for (int r = 0; r < 4; ++r) {
            uint rowA = (uint)(m0 + l4 * 4 + r);
#pragma unroll
            for (int j = 0; j < 4; ++j)
                A0[rowA * 68 + j * 16 + l15] = o[j][r];
            if (l15 == 0) { M0[rowA] = mrow[r]; L0[rowA] = lrow[r]; }
        }
    }
    __syncthreads();
    if (grp == 1) {
        float* Ob = O + ((size_t)batch * SEQ + q0) * DH;
#pragma unroll
        for (int r = 0; r < 4; ++r) {
            uint rowA = (uint)(m0 + l4 * 4 + r);
            float m1 = mrow[r], l1 = lrow[r];
            float m0r = M0[rowA], l0r = L0[rowA];
            float mn = fmaxf(m0r, m1);
            float s0 = __expf(m0r - mn), s1 = __expf(m1 - mn);
            float inv = 1.0f / (l0r * s0 + l1 * s1);
#pragma unroll
            for (int j = 0; j < 4; ++j) {
                float af = A0[rowA * 68 + j * 16 + l15] * s0 + o[j][r] * s1;
                Ob[rowA * DH + j * 16 + l15] = af * inv;
            }
        }
    }
}

// ============ launcher ============
extern "C" void kernel_launch(void* const* d_in, const int* in_sizes, int n_in,
                              void* d_out, int out_size, void* d_ws, size_t ws_size,
                              hipStream_t stream) {
    (void)n_in; (void)out_size;
    const float* x1 = (const float*)d_in[0];
    const float* x2 = (const float*)d_in[1];
    const float* x3 = (const float*)d_in[2];
    float* out = (float*)d_out;
    const int B = in_sizes[0] / (SEQ * DH);

    if (B == 2 && ws_size >= WS_NEED) {
        ushort* Kb = (ushort*)d_ws;
        ushort* Vt = (ushort*)((char*)d_ws + WS_VT);
        float* Opart = (float*)((char*)d_ws + WS_OP);
        float* Mlp = (float*)((char*)d_ws + WS_ML);
        prep_k2<<<512, 256, 0, stream>>>(x2, x3, Kb, Vt);
        attn_k2<<<512, 256, 0, stream>>>(x1, Kb, Vt, Opart, Mlp);
        merge_k2<<<512, 256, 0, stream>>>(Opart, Mlp, out);
    } else {
        attn_fwd_mfma<<<dim3(SEQ / BQ, B), 512, 0, stream>>>(x1, x2, x3, out);
    }
}